// Round 6
// baseline (110.526 us; speedup 1.0000x reference)
//
#include <hip/hip_runtime.h>

#define B 32
#define M 4096
#define N 8192
#define DC 10
#define NUM_ITERS 8
#define INV_TEMP 100.0f   // 1/TEMP, TEMP=0.01
#define ALPHA 100.0f
#define NB (N * B)        // 262144
#define MB (M * B)        // 131072

// Prologue: zero accum A0, init BOTH llrs buffers to prior (degree-0 variables:
// their llrs_t == prior for all t and final_kernel reads all n), build syn sign
// (M,B), build pg[n] = (1-gamma)*prior.
__global__ __launch_bounds__(256) void prologue_kernel(
    const float* __restrict__ syn,    // (B,M)
    const float* __restrict__ prior,  // (N,)
    const float* __restrict__ gamma,  // (N,)
    float* __restrict__ accumA,       // (N,B)
    float* __restrict__ L0,           // (N,B)
    float* __restrict__ L1,           // (N,B)
    float* __restrict__ syn_t,        // (M,B)
    float* __restrict__ pg)           // (N,)
{
    int idx = blockIdx.x * blockDim.x + threadIdx.x;
    if (idx < NB) {
        float p = prior[idx >> 5];
        accumA[idx] = 0.0f;
        L0[idx] = p;
        L1[idx] = p;
    }
    if (idx < MB) {
        int b = idx & 31, m = idx >> 5;
        syn_t[idx] = 1.0f - 2.0f * syn[(size_t)b * M + m];
    }
    if (idx < N) pg[idx] = (1.0f - gamma[idx]) * prior[idx];
}

// Edge-parallel fused check+var kernel. Block = 320 threads = one check m:
// i = tid>>5 (edge slot 0..9), b = tid&31 (batch). 4096 blocks -> 20480 waves
// (30/CU) vs thread-per-(m,b)'s 2048 (8/CU): trades 2x VALU work for 3.75x
// latency hiding. libm tanhf/expf (precision is load-bearing: the BP map is
// chaotic with slope ~ALPHA near v=0).
// KIND 0: t=0   v2c = prior[nb]
// KIND 1: t=1   llrs_0 = R + prior; v2c = llrs_0 - c2v; write Lnew
// KIND 2: t>=2  llrs   = R + pg + gamma*Lold; v2c = llrs - c2v; write Lnew
template <int KIND>
__global__ __launch_bounds__(320) void check_kernel(
    const float* __restrict__ syn_t,  // (M,B) sign form
    const float* __restrict__ prior,  // (N,)
    const float* __restrict__ pg,     // (N,)
    const float* __restrict__ gamma,  // (N,)
    const int*   __restrict__ nbrs,   // (M,DC)
    const float* __restrict__ R,      // accum_{t-1} (N,B)
    float*       __restrict__ W,      // accum_t (N,B), pre-zeroed
    float*       __restrict__ Z,      // accum buffer zeroed here for t+1
    const float* __restrict__ Lold,   // llrs_{t-2} (N,B)
    float*       __restrict__ Lnew,   // llrs_{t-1} (N,B)
    float*       __restrict__ c2v)    // (M,DC,B)
{
    __shared__ float sh_s[DC][32];
    __shared__ float sh_a[DC][32];

    const int m   = blockIdx.x;
    const int tid = threadIdx.x;
    const int i   = tid >> 5;
    const int b   = tid & 31;

    const int nb   = nbrs[m * DC + i];        // broadcast within 32-lane group
    const int goff = nb * B + b;              // (N,B) index
    const int eoff = (m * DC + i) * B + b;    // c2v index

    float v;
    if (KIND == 0) {
        v = prior[nb];
    } else if (KIND == 1) {
        float l = R[goff] + prior[nb];
        Lnew[goff] = l;                       // redundant identical writes: benign
        v = l - c2v[eoff];
    } else {
        float l = R[goff] + pg[nb] + gamma[nb] * Lold[goff];
        Lnew[goff] = l;
        v = l - c2v[eoff];
    }

    sh_s[i][b] = tanhf(ALPHA * v);            // smooth_sign, libm
    sh_a[i][b] = fabsf(v);

    // zero next iteration's accumulator while waiting for the barrier
    int gtid = m * 320 + tid;
    if (gtid < NB) Z[gtid] = 0.0f;

    __syncthreads();

    float sj[DC], aj[DC];
    #pragma unroll
    for (int j = 0; j < DC; ++j) { sj[j] = sh_s[j][b]; aj[j] = sh_a[j][b]; }

    // leave-one-out sign product and exact leave-one-out min
    float prod = 1.0f;
    float amin = 1e30f;
    #pragma unroll
    for (int j = 0; j < DC; ++j) {
        bool o = (j != i);
        prod *= o ? sj[j] : 1.0f;
        amin = fminf(amin, o ? aj[j] : 1e30f);
    }

    // leave-one-out softmin shifted by the exact LOO min (== reference softmax;
    // the excluded term is select-zeroed, uniform across the wave)
    float se = 0.0f, sae = 0.0f;
    #pragma unroll
    for (int j = 0; j < DC; ++j) {
        float e = expf((amin - aj[j]) * INV_TEMP);
        e = (j != i) ? e : 0.0f;
        se  += e;
        sae += aj[j] * e;
    }
    float me = sae / se;

    float out = syn_t[m * B + b] * prod * me;
    c2v[eoff] = out;
    atomicAdd(&W[goff], out);
}

// Epilogue: llrs_7 = accum_7 + pg + gamma*llrs_6, written transposed to d_out (B,N).
__global__ __launch_bounds__(256) void final_kernel(
    const float* __restrict__ R,     // accum_7 (N,B)
    const float* __restrict__ pg,    // (N,)
    const float* __restrict__ gamma, // (N,)
    const float* __restrict__ Lold,  // llrs_6 (N,B)
    float*       __restrict__ out)   // (B,N)
{
    int idx = blockIdx.x * blockDim.x + threadIdx.x;  // b*N + n (write-coalesced)
    if (idx >= NB) return;
    int n = idx & (N - 1);
    int b = idx >> 13;
    int goff = n * B + b;
    out[idx] = R[goff] + pg[n] + gamma[n] * Lold[goff];
}

extern "C" void kernel_launch(void* const* d_in, const int* in_sizes, int n_in,
                              void* d_out, int out_size, void* d_ws, size_t ws_size,
                              hipStream_t stream) {
    const float* syn   = (const float*)d_in[0];   // (B,M)
    const float* prior = (const float*)d_in[1];   // (N,)
    const float* gamma = (const float*)d_in[2];   // (N,)
    const int*   nbrs  = (const int*)d_in[3];     // (M,DC)
    float* out = (float*)d_out;                   // (B,N)

    float* ws = (float*)d_ws;
    float* A[3] = { ws, ws + NB, ws + 2 * (size_t)NB };          // accum rotation
    float* L[2] = { ws + 3 * (size_t)NB, ws + 4 * (size_t)NB };  // llrs double buffer
    float* c2v   = ws + 5 * (size_t)NB;                          // M*DC*B
    float* syn_t = c2v + (size_t)M * DC * B;                     // M*B
    float* pg    = syn_t + MB;                                   // N

    dim3 blk256(256);
    dim3 pgrid((NB + 255) / 256);
    dim3 cgrid(M);
    dim3 cblk(320);

    prologue_kernel<<<pgrid, blk256, 0, stream>>>(syn, prior, gamma, A[0], L[0], L[1], syn_t, pg);

    for (int t = 0; t < NUM_ITERS; ++t) {
        float* Rb = A[(t + 2) % 3];
        float* Wb = A[t % 3];
        float* Zb = A[(t + 1) % 3];
        float* Lo = L[t & 1];          // llrs_{t-2}
        float* Ln = L[(t + 1) & 1];    // llrs_{t-1}
        if (t == 0) {
            check_kernel<0><<<cgrid, cblk, 0, stream>>>(syn_t, prior, pg, gamma, nbrs,
                                                        nullptr, Wb, Zb, nullptr, nullptr, c2v);
        } else if (t == 1) {
            check_kernel<1><<<cgrid, cblk, 0, stream>>>(syn_t, prior, pg, gamma, nbrs,
                                                        Rb, Wb, Zb, nullptr, Ln, c2v);
        } else {
            check_kernel<2><<<cgrid, cblk, 0, stream>>>(syn_t, prior, pg, gamma, nbrs,
                                                        Rb, Wb, Zb, Lo, Ln, c2v);
        }
    }
    // after t=7: accum_7 = A[7%3] = A[1], llrs_6 = L[(7+1)&1] = L[0]
    final_kernel<<<pgrid, blk256, 0, stream>>>(A[1], pg, gamma, L[0], out);
}